// Round 8
// baseline (24.310 us; speedup 1.0000x reference)
//
#include <hip/hip_runtime.h>
#include <math.h>

#define BB 16
#define NN 256
#define DD 32
#define RG 4               // rows per pair block
#define BPB (NN / RG)      // pair blocks per batch = 64

// ---------------------------------------------------------------------------
// K0: per-node transform.
//   uT[((b*8+q)*NN + n)*4 + c] = (x[b,n] @ W_out[0:32])[4q+c]   (transposed)
//   xT[...]                    = x[b,n][4q+c]                    (transposed)
//   v[(b*NN+n)*DD + d]         = (x[b,n] @ W_out[32:64] + b_out)[d] (row-major)
// Transposed u/x give K1 coalesced per-column loads; row-major v (and x
// itself) give K1 wave-uniform row reads -> scalar s_load path.
// ---------------------------------------------------------------------------
__global__ __launch_bounds__(256) void uvT_kernel(
    const float* __restrict__ x,
    const float* __restrict__ W_out,
    const float* __restrict__ b_out,
    float* __restrict__ uT, float* __restrict__ xT, float* __restrict__ v)
{
    __shared__ float lxA[256];
    int t = threadIdx.x;
    int g0 = blockIdx.x * 8;            // first global node (b*NN+n)
    lxA[t] = x[(size_t)g0 * DD + t];    // coalesced: 8 nodes x 32 dims
    __syncthreads();

    int nl = t >> 5, d = t & 31;
    int b  = (g0 + nl) >> 8;
    int n  = (g0 + nl) & 255;
    float su = 0.f, sv = 0.f;
#pragma unroll
    for (int k = 0; k < DD; ++k) {
        float xv = lxA[nl * DD + k];    // LDS broadcast across d-lanes
        su += xv * W_out[k * DD + d];          // coalesced, L1-hot
        sv += xv * W_out[(k + DD) * DD + d];
    }
    int idxT = ((b * 8 + (d >> 2)) * NN + n) * 4 + (d & 3);
    uT[idxT] = su;
    xT[idxT] = lxA[nl * DD + d];
    v[(size_t)(g0 + nl) * DD + d] = sv + b_out[d];
}

// ---------------------------------------------------------------------------
// K1: pair kernel — zero LDS except 128B reduction scratch.
// Block = (b, rowgroup of 4 rows), 1024 blocks x 256 thr (4 blocks/CU).
// Column data (u_j, x_j): 16 coalesced dwordx4 loads -> VGPRs, held all rows.
// Row data (v_i, x_i): wave-uniform addresses -> scalar SMEM loads (separate
// pipe, no LDS/VMEM in the hot loop).
// Per pair: h=relu(u_j+v_i); e=relu(h.wc+bc); mlin=(i==j)?0:e; mp=x_i.x_j;
//           w=sigmoid(relu([mlin,mp]@W_f1+b_f1)@W_f2+b_f2); m=w*mlin+(1-w)*mp
// Writes pre-norm m to out (coalesced) + rowsum/rowsq (shuffle tree).
// ---------------------------------------------------------------------------
__global__ __launch_bounds__(256) void pair_kernel(
    const float* __restrict__ x,
    const float* __restrict__ uT, const float* __restrict__ xT,
    const float* __restrict__ v,
    const float* __restrict__ W_cat, const float* __restrict__ b_cat,
    const float* __restrict__ W_f1,  const float* __restrict__ b_f1,
    const float* __restrict__ W_f2,  const float* __restrict__ b_f2,
    float* __restrict__ rowsum, float* __restrict__ rowsq,
    float* __restrict__ out)
{
    __shared__ float red0[RG][4], red1[RG][4];

    const int t  = threadIdx.x;          // column j
    const int b  = blockIdx.x >> 6;
    const int i0 = (blockIdx.x & 63) * RG;

    const float4* uT4 = (const float4*)uT;
    const float4* xT4 = (const float4*)xT;

    float4 uj[8], xj[8];
#pragma unroll
    for (int q = 0; q < 8; ++q) {        // coalesced: lanes = consecutive nodes
        uj[q] = uT4[(b * 8 + q) * NN + t];
        xj[q] = xT4[(b * 8 + q) * NN + t];
    }

    // uniform weights -> scalar regs
    const float4* Wc4 = (const float4*)W_cat;
    float4 wc[8];
#pragma unroll
    for (int q = 0; q < 8; ++q) wc[q] = Wc4[q];
    float f1a[8], f1b[8], fb1[8], f2w[8];
#pragma unroll
    for (int k = 0; k < 8; ++k) {
        f1a[k] = W_f1[k];        // W_f1[0,k]
        f1b[k] = W_f1[8 + k];    // W_f1[1,k]
        fb1[k] = b_f1[k];
        f2w[k] = W_f2[k];
    }
    const float bcat = b_cat[0], bf2 = b_f2[0];

    const int lane = t & 63, wv = t >> 6;
#pragma unroll
    for (int r = 0; r < RG; ++r) {
        const int i = i0 + r;
        // wave-uniform row pointers -> scalar loads (SMEM pipe)
        const float4* vrow = (const float4*)(v + ((size_t)b * NN + i) * DD);
        const float4* xrow = (const float4*)(x + ((size_t)b * NN + i) * DD);
        float e = 0.f, mp = 0.f;
#pragma unroll
        for (int q = 0; q < 8; ++q) {
            float4 vi = vrow[q];
            float4 xi = xrow[q];
            float4 uu = uj[q], xx = xj[q];
            e += fmaxf(uu.x + vi.x, 0.f) * wc[q].x;
            e += fmaxf(uu.y + vi.y, 0.f) * wc[q].y;
            e += fmaxf(uu.z + vi.z, 0.f) * wc[q].z;
            e += fmaxf(uu.w + vi.w, 0.f) * wc[q].w;
            mp += xx.x * xi.x + xx.y * xi.y + xx.z * xi.z + xx.w * xi.w;
        }
        e = fmaxf(e + bcat, 0.f);
        float mlin = (t == i) ? 0.f : e;
        float s = bf2;
#pragma unroll
        for (int k = 0; k < 8; ++k)
            s += fmaxf(mlin * f1a[k] + mp * f1b[k] + fb1[k], 0.f) * f2w[k];
        float w = 1.f / (1.f + __expf(-s));
        float m = w * mlin + (1.f - w) * mp;

        out[((size_t)b * NN + i) * NN + t] = m;   // coalesced pre-norm store

        float sm = m, sq = m * m;                 // deterministic tree
#pragma unroll
        for (int off = 32; off; off >>= 1) {
            sm += __shfl_down(sm, off);
            sq += __shfl_down(sq, off);
        }
        if (lane == 0) { red0[r][wv] = sm; red1[r][wv] = sq; }
    }
    __syncthreads();
    if (t < RG) {
        rowsum[b * NN + i0 + t] = red0[t][0] + red0[t][1] + red0[t][2] + red0[t][3];
        rowsq [b * NN + i0 + t] = red1[t][0] + red1[t][1] + red1[t][2] + red1[t][3];
    }
}

// ---------------------------------------------------------------------------
// K2: redundant per-block batch stats (2KB rowsum/rowsq, L2-hot) via
//   sum(m2) = 2*sum(m);  sum(m2^2) = sum(m^2) + 3*N*sum_i(rowmean_i^2)
// then in-place: out[b,i,j] = (out[b,i,j] + rowmean_i - mu) * rstd.
// Same grid/mapping as K1 -> m re-read is XCD-local L2.
// ---------------------------------------------------------------------------
__global__ __launch_bounds__(256) void final_kernel(
    const float* __restrict__ rowsum, const float* __restrict__ rowsq,
    float* __restrict__ out)
{
    __shared__ float sred[12];
    __shared__ float stat[2];
    const int t  = threadIdx.x;
    const int b  = blockIdx.x >> 6;
    const int i0 = (blockIdx.x & 63) * RG;

    float rs = rowsum[b * NN + t];
    float rq = rowsq [b * NN + t];
    float rr = rs * (1.f / NN);
    float sM = rs, sQ = rq, sR = rr * rr;
#pragma unroll
    for (int off = 32; off; off >>= 1) {
        sM += __shfl_down(sM, off);
        sQ += __shfl_down(sQ, off);
        sR += __shfl_down(sR, off);
    }
    const int wave = t >> 6;
    if ((t & 63) == 0) { sred[wave] = sM; sred[4 + wave] = sQ; sred[8 + wave] = sR; }
    __syncthreads();
    if (t == 0) {
        float sumM  = sred[0] + sred[1] + sred[2] + sred[3];
        float sumQ  = sred[4] + sred[5] + sred[6] + sred[7];
        float sumR2 = sred[8] + sred[9] + sred[10] + sred[11];
        const float inv = 1.f / ((float)NN * (float)NN);
        float mu  = 2.f * sumM * inv;
        float ex2 = (sumQ + 3.f * (float)NN * sumR2) * inv;
        stat[0] = mu;
        stat[1] = rsqrtf(ex2 - mu * mu + 1e-5f);
    }
    __syncthreads();
    const float mu = stat[0], rstd = stat[1];
#pragma unroll
    for (int r = 0; r < RG; ++r) {
        int i = i0 + r;
        size_t base = ((size_t)b * NN + i) * NN;
        float ri = rowsum[b * NN + i] * (1.f / NN);   // uniform, L1-hot
        out[base + t] = (out[base + t] + ri - mu) * rstd;
    }
}

extern "C" void kernel_launch(void* const* d_in, const int* in_sizes, int n_in,
                              void* d_out, int out_size, void* d_ws, size_t ws_size,
                              hipStream_t stream)
{
    const float* x     = (const float*)d_in[0];
    const float* W_out = (const float*)d_in[1];
    const float* b_out = (const float*)d_in[2];
    const float* W_cat = (const float*)d_in[3];
    const float* b_cat = (const float*)d_in[4];
    const float* W_f1  = (const float*)d_in[5];
    const float* b_f1  = (const float*)d_in[6];
    const float* W_f2  = (const float*)d_in[7];
    const float* b_f2  = (const float*)d_in[8];

    float* ws     = (float*)d_ws;
    float* uT     = ws;                         // BB*NN*DD
    float* xT     = uT + BB * NN * DD;          // BB*NN*DD
    float* v      = xT + BB * NN * DD;          // BB*NN*DD
    float* rowsum = v + BB * NN * DD;           // BB*NN
    float* rowsq  = rowsum + BB * NN;           // BB*NN
    float* outp   = (float*)d_out;

    uvT_kernel  <<<BB * NN / 8, 256, 0, stream>>>(x, W_out, b_out, uT, xT, v);
    pair_kernel <<<BB * BPB, 256, 0, stream>>>(x, uT, xT, v, W_cat, b_cat,
                                               W_f1, b_f1, W_f2, b_f2,
                                               rowsum, rowsq, outp);
    final_kernel<<<BB * BPB, 256, 0, stream>>>(rowsum, rowsq, outp);
}